// Round 3
// baseline (789.809 us; speedup 1.0000x reference)
//
#include <hip/hip_runtime.h>

#define KD 25088   // 512*49
#define N_DIM 1000
#define ZS 28      // split-K factor

typedef __attribute__((ext_vector_type(8))) short bf16x8;
typedef __attribute__((ext_vector_type(4))) float f32x4;

// v_cvt_pk_bf16_f32: dst.lo=bf16(a), dst.hi=bf16(b) — RNE, 1 inst [T12, m214v22]
__device__ inline unsigned pack2(float a, float b) {
  unsigned r;
  asm("v_cvt_pk_bf16_f32 %0, %1, %2" : "=v"(r) : "v"(a), "v"(b));
  return r;
}
__device__ inline unsigned short f2bf(float x) {
  unsigned r;
  asm("v_cvt_pk_bf16_f32 %0, %1, %1" : "=v"(r) : "v"(x));
  return (unsigned short)r;
}
__device__ inline float bf2f(unsigned short u) {
  union { unsigned u; float f; } v; v.u = ((unsigned)u) << 16; return v.f;
}

// load 8 consecutive fp32 and convert to a bf16x8 fragment (2x dwordx4 + 4 cvt_pk)
__device__ inline bf16x8 ld_cvt8(const float* __restrict__ p) {
  union { bf16x8 v; unsigned u[4]; } r;
  const float4 a = *(const float4*)p;
  const float4 b = *(const float4*)(p + 4);
  r.u[0] = pack2(a.x, a.y);
  r.u[1] = pack2(a.z, a.w);
  r.u[2] = pack2(b.x, b.y);
  r.u[3] = pack2(b.z, b.w);
  return r.v;
}

// ---------------------------------------------------------------------------
// fallback-only: outR[m,n] = bias[n]
// ---------------------------------------------------------------------------
__global__ __launch_bounds__(256) void init_bias_k(
    const float* __restrict__ bias, float* __restrict__ outR) {
  const int id = blockIdx.x * 256 + threadIdx.x;
  if (id < 256 * N_DIM) outR[id] = bias[id % N_DIM];
}

// ---------------------------------------------------------------------------
// R-GEMM, direct-register (no LDS, no barriers): each lane's MFMA fragments
// are contiguous 8-float runs in A and W; load straight to VGPRs, cvt_pk to
// bf16 in-register, MFMA. Intra-block duplicate reads (2 waves share cw /
// jw rows) are L1-served. 28-way split-K unchanged; XCD swizzle unchanged.
// ---------------------------------------------------------------------------
template<int ATOMIC>
__global__ __launch_bounds__(256) void rgemm_k(
    const float* __restrict__ A, const float* __restrict__ W,
    float* __restrict__ D) {
  const int t = threadIdx.x;
  // bijective decode: id -> (xcd=id&7, j=id>>3); mz = xcd*7 + (j>>3); n = j&7
  const int id  = blockIdx.x;          // 0..447
  const int mz  = (id & 7) * 7 + ((id >> 3) >> 3);   // 0..55
  const int n0  = ((id >> 3) & 7) * 128;
  const int m0  = (mz / ZS) * 128;
  const int z   = mz % ZS;
  const int lane = t & 63, w = t >> 6;
  const int cw = (w >> 1) * 64, jw = (w & 1) * 64;
  const int r16 = lane & 15, quad = lane >> 4;
  const bool doj3 = (n0 + jw + 48) < N_DIM;   // j=3 fragment fully pad?

  f32x4 acc[4][4];
#pragma unroll
  for (int i = 0; i < 4; ++i)
#pragma unroll
    for (int j = 0; j < 4; ++j) {
      acc[i][j][0] = 0.f; acc[i][j][1] = 0.f;
      acc[i][j][2] = 0.f; acc[i][j][3] = 0.f;
    }

  // loop-invariant row bases (k-offset varies by imm-friendly s*128B)
  const float* arow[4];
  const float* wrow[4];
  bool wok[4];
#pragma unroll
  for (int i = 0; i < 4; ++i)
    arow[i] = A + (size_t)(m0 + cw + i * 16 + r16) * KD + (size_t)z * (ZS * 32) + quad * 8;
#pragma unroll
  for (int j = 0; j < 4; ++j) {
    const int n = n0 + jw + j * 16 + r16;
    wok[j] = (n < N_DIM);
    wrow[j] = W + (size_t)(wok[j] ? n : 0) * KD + (size_t)z * (ZS * 32) + quad * 8;
  }

  const bf16x8 zer = {0, 0, 0, 0, 0, 0, 0, 0};
  for (int s = 0; s < ZS; ++s) {
    const int k0 = s * 32;
    bf16x8 af[4], bq[4];
#pragma unroll
    for (int i = 0; i < 4; ++i) af[i] = ld_cvt8(arow[i] + k0);
#pragma unroll
    for (int j = 0; j < 4; ++j) {
      if (j == 3 && !doj3) { bq[j] = zer; continue; }
      bq[j] = wok[j] ? ld_cvt8(wrow[j] + k0) : zer;
    }
#pragma unroll
    for (int i = 0; i < 4; ++i)
#pragma unroll
      for (int j = 0; j < 4; ++j)
        if (j < 3 || doj3)
          acc[i][j] = __builtin_amdgcn_mfma_f32_16x16x32_bf16(af[i], bq[j], acc[i][j], 0, 0, 0);
  }

  // epilogue: C layout col=lane&15 (n), row=quad*4+r (m)   [m89-verified]
#pragma unroll
  for (int j = 0; j < 4; ++j) {
    const int n = n0 + jw + j * 16 + r16;
    if (n < N_DIM) {
#pragma unroll
      for (int i = 0; i < 4; ++i)
#pragma unroll
        for (int r = 0; r < 4; ++r) {
          const int m = m0 + cw + i * 16 + quad * 4 + r;
          if (ATOMIC)
            atomicAdd(&D[(size_t)m * N_DIM + n], acc[i][j][r]);
          else
            D[((size_t)z * 256 + m) * N_DIM + n] = acc[i][j][r];
        }
    }
  }
}

// ---------------------------------------------------------------------------
// top-8 per row. FROMPART=1: src=partials, reduce 28 z-planes + bias and
// write outR (absorbs init_bias + reduce). FROMPART=0: src=outR (fallback).
// ---------------------------------------------------------------------------
template<int FROMPART>
__global__ __launch_bounds__(64) void top8_k(
    const float* __restrict__ src, const float* __restrict__ bias,
    float* __restrict__ outR, int* __restrict__ top2,
    int* __restrict__ candIdx, int* __restrict__ flags,
    float* __restrict__ outSPD) {
  const int n = blockIdx.x;
  const int lane = threadIdx.x;
  float v[16];
  if (FROMPART) {
#pragma unroll
    for (int r = 0; r < 16; ++r) {
      const int o = lane + r * 64;
      v[r] = (o < N_DIM) ? bias[o] : -3.0e38f;
    }
    for (int z = 0; z < ZS; ++z) {
      const float* pz = src + ((size_t)z * 256 + n) * N_DIM;
#pragma unroll
      for (int r = 0; r < 16; ++r) {
        const int o = lane + r * 64;
        if (o < N_DIM) v[r] += pz[o];
      }
    }
#pragma unroll
    for (int r = 0; r < 16; ++r) {
      const int o = lane + r * 64;
      if (o < N_DIM) outR[(size_t)n * N_DIM + o] = v[r];
    }
  } else {
#pragma unroll
    for (int r = 0; r < 16; ++r) {
      const int o = lane + r * 64;
      v[r] = (o < N_DIM) ? src[(size_t)n * N_DIM + o] : -3.0e38f;
    }
  }
  float cv[8]; int ci[8];
#pragma unroll
  for (int rr = 0; rr < 8; ++rr) {
    float bv = -3.0e38f; int bi = 0x3fffffff;
#pragma unroll
    for (int r = 0; r < 16; ++r) {
      const int o = lane + r * 64;
      if (v[r] > bv || (v[r] == bv && o < bi)) { bv = v[r]; bi = o; }
    }
#pragma unroll
    for (int off = 32; off >= 1; off >>= 1) {
      const float ov = __shfl_xor(bv, off, 64);
      const int   oi = __shfl_xor(bi, off, 64);
      if (ov > bv || (ov == bv && oi < bi)) { bv = ov; bi = oi; }
    }
    cv[rr] = bv; ci[rr] = bi;
#pragma unroll
    for (int r = 0; r < 16; ++r)
      if (lane + r * 64 == bi) v[r] = -3.0e38f;
  }
  if (lane == 0) {
    const bool safe = (cv[0] - cv[1] >= 0.025f) &&
                      (cv[1] - cv[2] >= 0.025f) &&
                      (cv[1] - cv[7] >= 0.05f);
    flags[n] = safe ? 0 : 1;
    top2[2 * n]     = ci[0];
    top2[2 * n + 1] = ci[1];
#pragma unroll
    for (int r = 0; r < 8; ++r) candIdx[n * 8 + r] = ci[r];
    outSPD[4 * n + 0] = 0.f; outSPD[4 * n + 1] = 0.f;
    outSPD[4 * n + 2] = 0.f; outSPD[4 * n + 3] = 0.f;
  }
}

// ---------------------------------------------------------------------------
// exact fp32 dot for flagged (n, candidate) pairs -> vals[n*8+c]
// ---------------------------------------------------------------------------
__global__ __launch_bounds__(256) void rdot_k(
    const float* __restrict__ A, const float* __restrict__ W,
    const float* __restrict__ bias, const int* __restrict__ candIdx,
    const int* __restrict__ flags, float* __restrict__ vals) {
  const int n = blockIdx.x;
  if (!flags[n]) return;
  const int c = blockIdx.y;
  const int idx = candIdx[n * 8 + c];
  const float4* a4 = (const float4*)(A + (size_t)n * KD);
  const float4* w4 = (const float4*)(W + (size_t)idx * KD);
  float s = 0.f;
  for (int i = threadIdx.x; i < KD / 4; i += 256) {
    const float4 av = a4[i];
    const float4 wv = w4[i];
    s += av.x * wv.x + av.y * wv.y + av.z * wv.z + av.w * wv.w;
  }
#pragma unroll
  for (int off = 32; off >= 1; off >>= 1) s += __shfl_xor(s, off, 64);
  __shared__ float red[4];
  const int lane = threadIdx.x & 63, w = threadIdx.x >> 6;
  if (lane == 0) red[w] = s;
  __syncthreads();
  if (threadIdx.x == 0)
    vals[n * 8 + c] = red[0] + red[1] + red[2] + red[3] + bias[idx];
}

// ---------------------------------------------------------------------------
// fallback-only: final top-2 from exact vals for flagged rows
// ---------------------------------------------------------------------------
__global__ __launch_bounds__(64) void select_k(
    const float* __restrict__ vals, const int* __restrict__ candIdx,
    const int* __restrict__ flags, int* __restrict__ top2) {
  const int n = blockIdx.x;
  if (threadIdx.x != 0 || !flags[n]) return;
  int b0 = -1; float v0 = -3.0e38f; int i0 = 0x3fffffff;
  for (int c = 0; c < 8; ++c) {
    const int idx = candIdx[n * 8 + c];
    const float vv = vals[n * 8 + c];
    if (vv > v0 || (vv == v0 && idx < i0)) { v0 = vv; i0 = idx; b0 = c; }
  }
  float v1 = -3.0e38f; int i1 = 0x3fffffff;
  for (int c = 0; c < 8; ++c) {
    if (c == b0) continue;
    const int idx = candIdx[n * 8 + c];
    const float vv = vals[n * 8 + c];
    if (vv > v1 || (vv == v1 && idx < i1)) { v1 = vv; i1 = idx; }
  }
  top2[2 * n]     = i0;
  top2[2 * n + 1] = i1;
}

// ---------------------------------------------------------------------------
// pack + select fused: block (n, which). Thread 0 resolves final top-2, then
// block packs W[sel] -> Wp[n][which*49+hw][c] (bf16) via coalesced float4
// linear read + LDS transpose tile[hw][c] (stride 130) + coalesced 4B writes.
// ---------------------------------------------------------------------------
__global__ __launch_bounds__(256) void packsel_k(
    const float* __restrict__ W, const int* __restrict__ candIdx,
    const int* __restrict__ flags, const float* __restrict__ vals,
    unsigned short* __restrict__ Wp) {
  __shared__ unsigned short tile[49 * 130];
  __shared__ int sel_s;
  const int n = blockIdx.x;
  const int which = blockIdx.y;        // 0 -> ia rows 0..48, 1 -> ib rows 49..97
  const int t = threadIdx.x;
  if (t == 0) {
    int ia, ib;
    if (!flags[n]) {
      ia = candIdx[n * 8];
      ib = candIdx[n * 8 + 1];
    } else {
      int b0 = -1; float v0 = -3.0e38f; int i0 = 0x3fffffff;
      for (int c = 0; c < 8; ++c) {
        const int idx = candIdx[n * 8 + c];
        const float vv = vals[n * 8 + c];
        if (vv > v0 || (vv == v0 && idx < i0)) { v0 = vv; i0 = idx; b0 = c; }
      }
      float v1 = -3.0e38f; int i1 = 0x3fffffff;
      for (int c = 0; c < 8; ++c) {
        if (c == b0) continue;
        const int idx = candIdx[n * 8 + c];
        const float vv = vals[n * 8 + c];
        if (vv > v1 || (vv == v1 && idx < i1)) { v1 = vv; i1 = idx; }
      }
      ia = i0; ib = i1;
    }
    sel_s = which ? ib : ia;
  }
  unsigned short* dstn = Wp + (size_t)n * 65536;
  {
    // zero pad rows: which=0 -> 98..112, which=1 -> 113..127 (15 rows each)
    const int r0 = 98 + which * 15;
    for (int u = t; u < 15 * 128; u += 256) {
      const int rr = u >> 7;
      const int cc = (u & 127) << 1;
      *(unsigned*)(dstn + (size_t)(r0 + rr) * 512 + cc) = 0u;
    }
  }
  __syncthreads();
  const int sel = sel_s;
  const float4* src4 = (const float4*)(W + (size_t)sel * KD);
  for (int chunk = 0; chunk < 4; ++chunk) {        // 128 c-rows per chunk
    const float4* s4 = src4 + chunk * 1568;
    for (int u4 = t; u4 < 1568; u4 += 256) {
      const float4 fv = s4[u4];
      const float vv[4] = {fv.x, fv.y, fv.z, fv.w};
      const int i0 = u4 * 4;
#pragma unroll
      for (int e = 0; e < 4; ++e) {
        const int idx = i0 + e;
        const int c = idx / 49;
        const int hw = idx - c * 49;
        tile[hw * 130 + c] = f2bf(vv[e]);
      }
    }
    __syncthreads();
    const int cp = t & 63, hwb = t >> 6;
    unsigned short* wbase = dstn + (size_t)which * 49 * 512 + chunk * 128 + 2 * cp;
#pragma unroll
    for (int it = 0; it < 13; ++it) {
      const int hw = hwb + it * 4;
      if (hw < 49) {
        const unsigned val = *(const unsigned*)&tile[hw * 130 + 2 * cp];
        *(unsigned*)(wbase + (size_t)hw * 512) = val;
      }
    }
    __syncthreads();
  }
}

// ---------------------------------------------------------------------------
// SPD fast path, direct-register (no LDS in the K-loop, no barriers):
// af from S (fp32, cvt in-register), bq straight bf16x8 loads from Wp.
// Fold into 2x2 with bf16 Wp reads, atomic reduce. XCD swizzle unchanged.
// jw==64 waves skip the all-pad j=3 fragment (rows 112..127 are zeros).
// ---------------------------------------------------------------------------
__global__ __launch_bounds__(256) void spd_k(
    const float* __restrict__ S, const unsigned short* __restrict__ Wp,
    float* __restrict__ outSPD) {
  __shared__ float red[4];
  const int t = threadIdx.x;
  // bijective decode: id -> (xcd=id&7, j=id>>3); n = xcd*32 + (j>>2); c = j&3
  const int id = blockIdx.x;           // 0..1023
  const int n  = (id & 7) * 32 + ((id >> 3) >> 2);
  const int c0 = ((id >> 3) & 3) * 128;
  const float* Sn = S + (size_t)n * 512 * 512;
  const unsigned short* Wpn = Wp + (size_t)n * 65536;
  const int lane = t & 63, w = t >> 6;
  const int cw = (w >> 1) * 64, jw = (w & 1) * 64;
  const int r16 = lane & 15, quad = lane >> 4;
  const bool doj3 = (jw == 0);         // jw==64: j=3 covers rows 112..127 (pad)

  if (t < 4) red[t] = 0.f;

  f32x4 acc[4][4];
#pragma unroll
  for (int i = 0; i < 4; ++i)
#pragma unroll
    for (int j = 0; j < 4; ++j) {
      acc[i][j][0] = 0.f; acc[i][j][1] = 0.f;
      acc[i][j][2] = 0.f; acc[i][j][3] = 0.f;
    }

  const float* sbase = Sn + (size_t)(c0 + cw + r16) * 512 + quad * 8;
  const unsigned short* wbase = Wpn + (size_t)(jw + r16) * 512 + quad * 8;

  for (int s = 0; s < 16; ++s) {
    const int k0 = s * 32;
    bf16x8 af[4], bq[4];
#pragma unroll
    for (int i = 0; i < 4; ++i)
      af[i] = ld_cvt8(sbase + (size_t)i * 16 * 512 + k0);
#pragma unroll
    for (int j = 0; j < 4; ++j)
      if (j < 3 || doj3)
        bq[j] = *(const bf16x8*)(wbase + (size_t)j * 16 * 512 + k0);
#pragma unroll
    for (int i = 0; i < 4; ++i)
#pragma unroll
      for (int j = 0; j < 4; ++j)
        if (j < 3 || doj3)
          acc[i][j] = __builtin_amdgcn_mfma_f32_16x16x32_bf16(af[i], bq[j], acc[i][j], 0, 0, 0);
  }

  __syncthreads();   // red[] init visible before fold atomics

  // fold: C layout col=lane&15 (j), row=quad*4+r (c)
  float p00 = 0.f, p01 = 0.f, p10 = 0.f, p11 = 0.f;
#pragma unroll
  for (int j = 0; j < 4; ++j) {
    const int jj = jw + j * 16 + r16;
    if (jj < 98) {
      const int kk = (jj >= 49);
      const int hw = jj - 49 * kk;
      const unsigned short* wa = Wpn + (size_t)hw * 512;         // W[ia][c,hw]
      const unsigned short* wb = Wpn + (size_t)(49 + hw) * 512;  // W[ib][c,hw]
#pragma unroll
      for (int i = 0; i < 4; ++i) {
#pragma unroll
        for (int r = 0; r < 4; ++r) {
          const int c = c0 + cw + i * 16 + quad * 4 + r;
          const float u   = acc[i][j][r];
          const float wav = bf2f(wa[c]);
          const float wbv = bf2f(wb[c]);
          if (kk == 0) { p00 = fmaf(u, wav, p00); p01 = fmaf(u, wbv, p01); }
          else         { p10 = fmaf(u, wav, p10); p11 = fmaf(u, wbv, p11); }
        }
      }
    }
  }

  atomicAdd(&red[0], p00);
  atomicAdd(&red[1], p01);
  atomicAdd(&red[2], p10);
  atomicAdd(&red[3], p11);
  __syncthreads();
  if (t < 4) atomicAdd(&outSPD[n * 4 + t], red[t]);
}

// ---------------------------------------------------------------------------
// SPD fallback (no workspace needed beyond the small scratch)
// ---------------------------------------------------------------------------
__global__ __launch_bounds__(256) void spd_fb_k(
    const float* __restrict__ S, const float* __restrict__ W,
    const int* __restrict__ top2, float* __restrict__ outSPD) {
  __shared__ unsigned short As[128 * 40];
  __shared__ unsigned short Bs[128 * 40];
  __shared__ float red[4];
  const int t = threadIdx.x;
  const int n  = blockIdx.x >> 2;
  const int c0 = (blockIdx.x & 3) * 128;
  const int ia = top2[2 * n];
  const int ib = top2[2 * n + 1];
  const float* Sn = S + (size_t)n * 512 * 512;
  const int lane = t & 63, w = t >> 6;
  const int cw = (w >> 1) * 64, jw = (w & 1) * 64;
  const int r16 = lane & 15, quad = lane >> 4;
  if (t < 4) red[t] = 0.f;
  f32x4 acc[4][4];
#pragma unroll
  for (int i = 0; i < 4; ++i)
#pragma unroll
    for (int j = 0; j < 4; ++j) {
      acc[i][j][0] = 0.f; acc[i][j][1] = 0.f;
      acc[i][j][2] = 0.f; acc[i][j][3] = 0.f;
    }
  const int bj  = t & 127;
  const int bh  = t >> 7;
  const int bkk = (bj >= 49);
  const int bhw = bj - 49 * bkk;
  const bool bvalid = (bj < 98);
  const float* brow = W + (size_t)(bkk ? ib : ia) * KD + bhw;
  for (int d0 = 0; d0 < 512; d0 += 32) {
#pragma unroll
    for (int h = 0; h < 4; ++h) {
      const int idx = h * 256 + t;
      const int row = idx >> 3;
      const int c4  = (idx & 7) << 2;
      float4 av = *(const float4*)(Sn + (size_t)(c0 + row) * 512 + d0 + c4);
      uint2 pa;
      pa.x = pack2(av.x, av.y);
      pa.y = pack2(av.z, av.w);
      *(uint2*)&As[row * 40 + c4] = pa;
    }
#pragma unroll
    for (int dd2 = 0; dd2 < 16; dd2 += 2) {
      const int dd = bh * 16 + dd2;
      const float x0 = bvalid ? brow[(size_t)(d0 + dd) * 49] : 0.f;
      const float x1 = bvalid ? brow[(size_t)(d0 + dd + 1) * 49] : 0.f;
      *(unsigned*)&Bs[bj * 40 + dd] = pack2(x0, x1);
    }
    __syncthreads();
    bf16x8 af[4], bq[4];
#pragma unroll
    for (int i = 0; i < 4; ++i) {
      af[i] = *(const bf16x8*)&As[(cw + i * 16 + r16) * 40 + quad * 8];
      bq[i] = *(const bf16x8*)&Bs[(jw + i * 16 + r16) * 40 + quad * 8];
    }
#pragma unroll
    for (int i = 0; i < 4; ++i)
#pragma unroll
      for (int j = 0; j < 4; ++j)
        acc[i][j] = __builtin_amdgcn_mfma_f32_16x16x32_bf16(af[i], bq[j], acc[i][j], 0, 0, 0);
    __syncthreads();
  }
  float p00 = 0.f, p01 = 0.f, p10 = 0.f, p11 = 0.f;
  const float* Wa = W + (size_t)ia * KD;
  const float* Wb = W + (size_t)ib * KD;
#pragma unroll
  for (int j = 0; j < 4; ++j) {
    const int jj = jw + j * 16 + r16;
    if (jj < 98) {
      const int kk = (jj >= 49);
      const int hw = jj - 49 * kk;
#pragma unroll
      for (int i = 0; i < 4; ++i)
#pragma unroll
        for (int r = 0; r < 4; ++r) {
          const int c = c0 + cw + i * 16 + quad * 4 + r;
          const float u  = acc[i][j][r];
          const float wa = Wa[(size_t)c * 49 + hw];
          const float wb = Wb[(size_t)c * 49 + hw];
          if (kk == 0) { p00 = fmaf(u, wa, p00); p01 = fmaf(u, wb, p01); }
          else         { p10 = fmaf(u, wa, p10); p11 = fmaf(u, wb, p11); }
        }
    }
  }
  atomicAdd(&red[0], p00);
  atomicAdd(&red[1], p01);
  atomicAdd(&red[2], p10);
  atomicAdd(&red[3], p11);
  __syncthreads();
  if (t < 4) atomicAdd(&outSPD[n * 4 + t], red[t]);
}

// ---------------------------------------------------------------------------
extern "C" void kernel_launch(void* const* d_in, const int* in_sizes, int n_in,
                              void* d_out, int out_size, void* d_ws, size_t ws_size,
                              hipStream_t stream) {
  const float* inputR   = (const float*)d_in[0];
  const float* inputSPD = (const float*)d_in[1];
  const float* weight   = (const float*)d_in[2];
  const float* bias     = (const float*)d_in[3];
  float* out = (float*)d_out;

  // ws: [top2 2K][cand 8K][flags 1K][vals 8K] .. 64K ..
  //     [part 28*256*1000*4 = 28.672 MB][Wp 33.55 MB]
  int*   top2    = (int*)d_ws;
  int*   candIdx = (int*)((char*)d_ws + 2048);
  int*   flags   = (int*)((char*)d_ws + 2048 + 8192);
  float* vals    = (float*)((char*)d_ws + 2048 + 8192 + 1024);
  float* part    = (float*)((char*)d_ws + 65536);
  const size_t PART_BYTES = (size_t)ZS * 256 * N_DIM * 4;          // 28,672,000
  unsigned short* Wp = (unsigned short*)((char*)d_ws + 65536 + PART_BYTES);
  const bool bigws = ws_size >= 65536ull + PART_BYTES + 256ull * 65536ull * 2ull;

  if (bigws) {
    rgemm_k<0><<<dim3(448), 256, 0, stream>>>(inputR, weight, part);
    top8_k<1><<<dim3(256), 64, 0, stream>>>(part, bias, out, top2, candIdx, flags, out + 256000);
    rdot_k<<<dim3(256, 8), 256, 0, stream>>>(inputR, weight, bias, candIdx, flags, vals);
    packsel_k<<<dim3(256, 2), 256, 0, stream>>>(weight, candIdx, flags, vals, Wp);
    spd_k<<<dim3(1024), 256, 0, stream>>>(inputSPD, Wp, out + 256000);
  } else {
    init_bias_k<<<dim3(1000), 256, 0, stream>>>(bias, out);
    rgemm_k<1><<<dim3(448), 256, 0, stream>>>(inputR, weight, out);
    top8_k<0><<<dim3(256), 64, 0, stream>>>(out, bias, out, top2, candIdx, flags, out + 256000);
    rdot_k<<<dim3(256, 8), 256, 0, stream>>>(inputR, weight, bias, candIdx, flags, vals);
    select_k<<<dim3(256), 64, 0, stream>>>(vals, candIdx, flags, top2);
    spd_fb_k<<<dim3(1024), 256, 0, stream>>>(inputSPD, weight, top2, out + 256000);
  }
}

// Round 4
// 532.175 us; speedup vs baseline: 1.4841x; 1.4841x over previous
//
#include <hip/hip_runtime.h>

#define KD 25088   // 512*49
#define N_DIM 1000
#define ZS 28      // split-K factor

typedef __attribute__((ext_vector_type(8))) short bf16x8;
typedef __attribute__((ext_vector_type(4))) float f32x4;

// v_cvt_pk_bf16_f32: dst.lo=bf16(a), dst.hi=bf16(b) — RNE, 1 inst [T12, m214v22]
__device__ inline unsigned pack2(float a, float b) {
  unsigned r;
  asm("v_cvt_pk_bf16_f32 %0, %1, %2" : "=v"(r) : "v"(a), "v"(b));
  return r;
}
__device__ inline unsigned short f2bf(float x) {
  unsigned r;
  asm("v_cvt_pk_bf16_f32 %0, %1, %1" : "=v"(r) : "v"(x));
  return (unsigned short)r;
}
__device__ inline float bf2f(unsigned short u) {
  union { unsigned u; float f; } v; v.u = ((unsigned)u) << 16; return v.f;
}

// ---------------------------------------------------------------------------
// fallback-only: outR[m,n] = bias[n]
// ---------------------------------------------------------------------------
__global__ __launch_bounds__(256) void init_bias_k(
    const float* __restrict__ bias, float* __restrict__ outR) {
  const int id = blockIdx.x * 256 + threadIdx.x;
  if (id < 256 * N_DIM) outR[id] = bias[id % N_DIM];
}

// ---------------------------------------------------------------------------
// fast-path: outR = bias + sum_z part[z]  (wide-parallel, fully coalesced)
// 250 blocks x 256 thr, one float4 per thread, 28 independent loads deep.
// ---------------------------------------------------------------------------
__global__ __launch_bounds__(256) void reduce_k(
    const float* __restrict__ part, const float* __restrict__ bias,
    float* __restrict__ outR) {
  const int t4 = blockIdx.x * 256 + threadIdx.x;   // 0..63999
  const int e0 = t4 * 4;
  const int n0 = e0 % N_DIM;                       // 1000 % 4 == 0 -> aligned
  float4 acc = *(const float4*)(bias + n0);
#pragma unroll
  for (int z = 0; z < ZS; ++z) {
    const float4 pv = *(const float4*)(part + (size_t)z * 256 * N_DIM + e0);
    acc.x += pv.x; acc.y += pv.y; acc.z += pv.z; acc.w += pv.w;
  }
  *(float4*)(outR + e0) = acc;
}

// ---------------------------------------------------------------------------
// R-GEMM: fixed 28-way split-K. ATOMIC=1: fp32 atomics into outR (fallback).
// ATOMIC=0: non-atomic stores into partials ws [z][m][n] (reduced in reduce_k).
// 128x128 tile, BK=32, 4 waves, double-buffered LDS, v_cvt_pk bf16 staging.
// XCD swizzle: all 8 n-blocks sharing an (m,z) A-slice land consecutively on
// one XCD (7 pairs x 458KB = 3.2MB < 4MB L2; 56 blocks/XCD co-resident).
// [R3 lesson: LDS staging is load-COALESCING, not dedup — keep it.]
// ---------------------------------------------------------------------------
template<int ATOMIC>
__global__ __launch_bounds__(256) void rgemm_k(
    const float* __restrict__ A, const float* __restrict__ W,
    float* __restrict__ D) {
  __shared__ unsigned short As[2][128 * 32];
  __shared__ unsigned short Bs[2][128 * 32];
  const int t = threadIdx.x;
  // bijective decode: id -> (xcd=id&7, j=id>>3); mz = xcd*7 + (j>>3); n = j&7
  const int id  = blockIdx.x;          // 0..447
  const int mz  = (id & 7) * 7 + ((id >> 3) >> 3);   // 0..55
  const int n0  = ((id >> 3) & 7) * 128;
  const int m0  = (mz / ZS) * 128;
  const int z   = mz % ZS;
  const int lane = t & 63, w = t >> 6;
  const int cw = (w >> 1) * 64, jw = (w & 1) * 64;
  const int r16 = lane & 15, quad = lane >> 4;
  const int srow = t >> 2;           // 0..63
  const int sc8  = (t & 3) << 3;     // 0,8,16,24
  const bool doj3 = (n0 + jw + 48) < N_DIM;   // j=3 fragment fully pad?

  float a_pre[16], b_pre[16];

  f32x4 acc[4][4];
#pragma unroll
  for (int i = 0; i < 4; ++i)
#pragma unroll
    for (int j = 0; j < 4; ++j) {
      acc[i][j][0] = 0.f; acc[i][j][1] = 0.f;
      acc[i][j][2] = 0.f; acc[i][j][3] = 0.f;
    }

#define RG_LOAD(s_)                                                         \
  {                                                                         \
    const int kbase = ((z) * ZS + (s_)) * 32;                               \
    _Pragma("unroll")                                                       \
    for (int h = 0; h < 2; ++h) {                                           \
      const int row = h * 64 + srow;                                        \
      const float* pa = A + (size_t)(m0 + row) * KD + kbase + sc8;          \
      *(float4*)&a_pre[h * 8 + 0] = *(const float4*)pa;                     \
      *(float4*)&a_pre[h * 8 + 4] = *(const float4*)(pa + 4);               \
      const int wr = n0 + row;                                              \
      if (wr < N_DIM) {                                                     \
        const float* pw = W + (size_t)wr * KD + kbase + sc8;                \
        *(float4*)&b_pre[h * 8 + 0] = *(const float4*)pw;                   \
        *(float4*)&b_pre[h * 8 + 4] = *(const float4*)(pw + 4);             \
      } else {                                                              \
        _Pragma("unroll")                                                   \
        for (int q = 0; q < 8; ++q) b_pre[h * 8 + q] = 0.f;                 \
      }                                                                     \
    }                                                                       \
  }

#define RG_WRITE(p_)                                                        \
  {                                                                         \
    _Pragma("unroll")                                                       \
    for (int h = 0; h < 2; ++h) {                                           \
      const int row = h * 64 + srow;                                        \
      uint4 ua, ub;                                                         \
      ua.x = pack2(a_pre[h*8+0], a_pre[h*8+1]);                             \
      ua.y = pack2(a_pre[h*8+2], a_pre[h*8+3]);                             \
      ua.z = pack2(a_pre[h*8+4], a_pre[h*8+5]);                             \
      ua.w = pack2(a_pre[h*8+6], a_pre[h*8+7]);                             \
      ub.x = pack2(b_pre[h*8+0], b_pre[h*8+1]);                             \
      ub.y = pack2(b_pre[h*8+2], b_pre[h*8+3]);                             \
      ub.z = pack2(b_pre[h*8+4], b_pre[h*8+5]);                             \
      ub.w = pack2(b_pre[h*8+6], b_pre[h*8+7]);                             \
      *(uint4*)&As[p_][row * 32 + sc8] = ua;                                \
      *(uint4*)&Bs[p_][row * 32 + sc8] = ub;                                \
    }                                                                       \
  }

  RG_LOAD(0); RG_WRITE(0); __syncthreads();
  int p = 0;
  for (int s = 0; s < ZS; ++s) {
    if (s + 1 < ZS) RG_LOAD(s + 1);
    bf16x8 af[4], bq[4];
#pragma unroll
    for (int i = 0; i < 4; ++i) {
      af[i] = *(const bf16x8*)&As[p][(cw + i * 16 + r16) * 32 + quad * 8];
      if (i < 3 || doj3)
        bq[i] = *(const bf16x8*)&Bs[p][(jw + i * 16 + r16) * 32 + quad * 8];
    }
#pragma unroll
    for (int i = 0; i < 4; ++i)
#pragma unroll
      for (int j = 0; j < 4; ++j)
        if (j < 3 || doj3)
          acc[i][j] = __builtin_amdgcn_mfma_f32_16x16x32_bf16(af[i], bq[j], acc[i][j], 0, 0, 0);
    if (s + 1 < ZS) RG_WRITE(p ^ 1);
    __syncthreads();
    p ^= 1;
  }

  // epilogue: C layout col=lane&15 (n), row=quad*4+r (m)   [m89-verified]
#pragma unroll
  for (int j = 0; j < 4; ++j) {
    const int n = n0 + jw + j * 16 + r16;
    if (n < N_DIM) {
#pragma unroll
      for (int i = 0; i < 4; ++i)
#pragma unroll
        for (int r = 0; r < 4; ++r) {
          const int m = m0 + cw + i * 16 + quad * 4 + r;
          if (ATOMIC)
            atomicAdd(&D[(size_t)m * N_DIM + n], acc[i][j][r]);
          else
            D[((size_t)z * 256 + m) * N_DIM + n] = acc[i][j][r];
        }
    }
  }
#undef RG_LOAD
#undef RG_WRITE
}

// ---------------------------------------------------------------------------
// top-8 per row, reading outR (already bias+reduced). Emits provisional top2,
// 8 candidates, recheck flag; zeroes outSPD.
// ---------------------------------------------------------------------------
__global__ __launch_bounds__(64) void top8_k(
    const float* __restrict__ outR, int* __restrict__ top2,
    int* __restrict__ candIdx, int* __restrict__ flags,
    float* __restrict__ outSPD) {
  const int n = blockIdx.x;
  const int lane = threadIdx.x;
  float v[16];
#pragma unroll
  for (int r = 0; r < 16; ++r) {
    const int o = lane + r * 64;
    v[r] = (o < N_DIM) ? outR[(size_t)n * N_DIM + o] : -3.0e38f;
  }
  float cv[8]; int ci[8];
#pragma unroll
  for (int rr = 0; rr < 8; ++rr) {
    float bv = -3.0e38f; int bi = 0x3fffffff;
#pragma unroll
    for (int r = 0; r < 16; ++r) {
      const int o = lane + r * 64;
      if (v[r] > bv || (v[r] == bv && o < bi)) { bv = v[r]; bi = o; }
    }
#pragma unroll
    for (int off = 32; off >= 1; off >>= 1) {
      const float ov = __shfl_xor(bv, off, 64);
      const int   oi = __shfl_xor(bi, off, 64);
      if (ov > bv || (ov == bv && oi < bi)) { bv = ov; bi = oi; }
    }
    cv[rr] = bv; ci[rr] = bi;
#pragma unroll
    for (int r = 0; r < 16; ++r)
      if (lane + r * 64 == bi) v[r] = -3.0e38f;
  }
  if (lane == 0) {
    const bool safe = (cv[0] - cv[1] >= 0.025f) &&
                      (cv[1] - cv[2] >= 0.025f) &&
                      (cv[1] - cv[7] >= 0.05f);
    flags[n] = safe ? 0 : 1;
    top2[2 * n]     = ci[0];
    top2[2 * n + 1] = ci[1];
#pragma unroll
    for (int r = 0; r < 8; ++r) candIdx[n * 8 + r] = ci[r];
    outSPD[4 * n + 0] = 0.f; outSPD[4 * n + 1] = 0.f;
    outSPD[4 * n + 2] = 0.f; outSPD[4 * n + 3] = 0.f;
  }
}

// ---------------------------------------------------------------------------
// exact fp32 dot for flagged (n, candidate) pairs -> vals[n*8+c]
// ---------------------------------------------------------------------------
__global__ __launch_bounds__(256) void rdot_k(
    const float* __restrict__ A, const float* __restrict__ W,
    const float* __restrict__ bias, const int* __restrict__ candIdx,
    const int* __restrict__ flags, float* __restrict__ vals) {
  const int n = blockIdx.x;
  if (!flags[n]) return;
  const int c = blockIdx.y;
  const int idx = candIdx[n * 8 + c];
  const float4* a4 = (const float4*)(A + (size_t)n * KD);
  const float4* w4 = (const float4*)(W + (size_t)idx * KD);
  float s = 0.f;
  for (int i = threadIdx.x; i < KD / 4; i += 256) {
    const float4 av = a4[i];
    const float4 wv = w4[i];
    s += av.x * wv.x + av.y * wv.y + av.z * wv.z + av.w * wv.w;
  }
#pragma unroll
  for (int off = 32; off >= 1; off >>= 1) s += __shfl_xor(s, off, 64);
  __shared__ float red[4];
  const int lane = threadIdx.x & 63, w = threadIdx.x >> 6;
  if (lane == 0) red[w] = s;
  __syncthreads();
  if (threadIdx.x == 0)
    vals[n * 8 + c] = red[0] + red[1] + red[2] + red[3] + bias[idx];
}

// ---------------------------------------------------------------------------
// fallback-only: final top-2 from exact vals for flagged rows
// ---------------------------------------------------------------------------
__global__ __launch_bounds__(64) void select_k(
    const float* __restrict__ vals, const int* __restrict__ candIdx,
    const int* __restrict__ flags, int* __restrict__ top2) {
  const int n = blockIdx.x;
  if (threadIdx.x != 0 || !flags[n]) return;
  int b0 = -1; float v0 = -3.0e38f; int i0 = 0x3fffffff;
  for (int c = 0; c < 8; ++c) {
    const int idx = candIdx[n * 8 + c];
    const float vv = vals[n * 8 + c];
    if (vv > v0 || (vv == v0 && idx < i0)) { v0 = vv; i0 = idx; b0 = c; }
  }
  float v1 = -3.0e38f; int i1 = 0x3fffffff;
  for (int c = 0; c < 8; ++c) {
    if (c == b0) continue;
    const int idx = candIdx[n * 8 + c];
    const float vv = vals[n * 8 + c];
    if (vv > v1 || (vv == v1 && idx < i1)) { v1 = vv; i1 = idx; }
  }
  top2[2 * n]     = i0;
  top2[2 * n + 1] = i1;
}

// ---------------------------------------------------------------------------
// pack + select fused: block (n, which). Thread 0 resolves final top-2, then
// block packs W[sel] -> Wp[n][which*49+hw][c] (bf16) via coalesced float4
// linear read + LDS transpose tile[hw][c] (stride 130) + coalesced 4B writes.
// ---------------------------------------------------------------------------
__global__ __launch_bounds__(256) void packsel_k(
    const float* __restrict__ W, const int* __restrict__ candIdx,
    const int* __restrict__ flags, const float* __restrict__ vals,
    unsigned short* __restrict__ Wp) {
  __shared__ unsigned short tile[49 * 130];
  __shared__ int sel_s;
  const int n = blockIdx.x;
  const int which = blockIdx.y;        // 0 -> ia rows 0..48, 1 -> ib rows 49..97
  const int t = threadIdx.x;
  if (t == 0) {
    int ia, ib;
    if (!flags[n]) {
      ia = candIdx[n * 8];
      ib = candIdx[n * 8 + 1];
    } else {
      int b0 = -1; float v0 = -3.0e38f; int i0 = 0x3fffffff;
      for (int c = 0; c < 8; ++c) {
        const int idx = candIdx[n * 8 + c];
        const float vv = vals[n * 8 + c];
        if (vv > v0 || (vv == v0 && idx < i0)) { v0 = vv; i0 = idx; b0 = c; }
      }
      float v1 = -3.0e38f; int i1 = 0x3fffffff;
      for (int c = 0; c < 8; ++c) {
        if (c == b0) continue;
        const int idx = candIdx[n * 8 + c];
        const float vv = vals[n * 8 + c];
        if (vv > v1 || (vv == v1 && idx < i1)) { v1 = vv; i1 = idx; }
      }
      ia = i0; ib = i1;
    }
    sel_s = which ? ib : ia;
  }
  unsigned short* dstn = Wp + (size_t)n * 65536;
  {
    // zero pad rows: which=0 -> 98..112, which=1 -> 113..127 (15 rows each)
    const int r0 = 98 + which * 15;
    for (int u = t; u < 15 * 128; u += 256) {
      const int rr = u >> 7;
      const int cc = (u & 127) << 1;
      *(unsigned*)(dstn + (size_t)(r0 + rr) * 512 + cc) = 0u;
    }
  }
  __syncthreads();
  const int sel = sel_s;
  const float4* src4 = (const float4*)(W + (size_t)sel * KD);
  for (int chunk = 0; chunk < 4; ++chunk) {        // 128 c-rows per chunk
    const float4* s4 = src4 + chunk * 1568;
    for (int u4 = t; u4 < 1568; u4 += 256) {
      const float4 fv = s4[u4];
      const float vv[4] = {fv.x, fv.y, fv.z, fv.w};
      const int i0 = u4 * 4;
#pragma unroll
      for (int e = 0; e < 4; ++e) {
        const int idx = i0 + e;
        const int c = idx / 49;
        const int hw = idx - c * 49;
        tile[hw * 130 + c] = f2bf(vv[e]);
      }
    }
    __syncthreads();
    const int cp = t & 63, hwb = t >> 6;
    unsigned short* wbase = dstn + (size_t)which * 49 * 512 + chunk * 128 + 2 * cp;
#pragma unroll
    for (int it = 0; it < 13; ++it) {
      const int hw = hwb + it * 4;
      if (hw < 49) {
        const unsigned val = *(const unsigned*)&tile[hw * 130 + 2 * cp];
        *(unsigned*)(wbase + (size_t)hw * 512) = val;
      }
    }
    __syncthreads();
  }
}

// ---------------------------------------------------------------------------
// SPD fast path: per (n, c-tile 128): U = S_tile x Wp^T via bf16 MFMA.
// A (S, fp32 HBM stream) staged through LDS for coalescing [R3 lesson];
// B (Wp, bf16, L2-resident 128KB/n) read DIRECTLY from global in fragment
// layout — no Bs staging, half the LDS, fewer staging instructions.
// XCD swizzle: 4 c-blocks of one n consecutive on one XCD (Wp L2-shared).
// jw==64 waves skip the all-pad j=3 fragment (rows 112..127 are zeros).
// ---------------------------------------------------------------------------
__global__ __launch_bounds__(256) void spd_k(
    const float* __restrict__ S, const unsigned short* __restrict__ Wp,
    float* __restrict__ outSPD) {
  __shared__ unsigned short As[2][128 * 32];
  __shared__ float red[4];
  const int t = threadIdx.x;
  // bijective decode: id -> (xcd=id&7, j=id>>3); n = xcd*32 + (j>>2); c = j&3
  const int id = blockIdx.x;           // 0..1023
  const int n  = (id & 7) * 32 + ((id >> 3) >> 2);
  const int c0 = ((id >> 3) & 3) * 128;
  const float* Sn = S + (size_t)n * 512 * 512;
  const unsigned short* Wpn = Wp + (size_t)n * 65536;
  const int lane = t & 63, w = t >> 6;
  const int cw = (w >> 1) * 64, jw = (w & 1) * 64;
  const int r16 = lane & 15, quad = lane >> 4;
  const int srow = t >> 2;
  const int sc8  = (t & 3) << 3;
  const bool doj3 = (jw == 0);         // jw==64: j=3 covers rows 112..127 (pad)

  if (t < 4) red[t] = 0.f;

  float a_pre[16];

  f32x4 acc[4][4];
#pragma unroll
  for (int i = 0; i < 4; ++i)
#pragma unroll
    for (int j = 0; j < 4; ++j) {
      acc[i][j][0] = 0.f; acc[i][j][1] = 0.f;
      acc[i][j][2] = 0.f; acc[i][j][3] = 0.f;
    }

  // loop-invariant B fragment bases (bf16, already in fragment layout)
  const unsigned short* wjb[4];
#pragma unroll
  for (int j = 0; j < 4; ++j)
    wjb[j] = Wpn + (size_t)(jw + j * 16 + r16) * 512 + quad * 8;

#define SP_LOAD(s_)                                                         \
  {                                                                         \
    const int d0 = (s_) * 32;                                               \
    _Pragma("unroll")                                                       \
    for (int h = 0; h < 2; ++h) {                                           \
      const int row = h * 64 + srow;                                        \
      const float* pa = Sn + (size_t)(c0 + row) * 512 + d0 + sc8;           \
      *(float4*)&a_pre[h * 8 + 0] = *(const float4*)pa;                     \
      *(float4*)&a_pre[h * 8 + 4] = *(const float4*)(pa + 4);               \
    }                                                                       \
  }

#define SP_WRITE(p_)                                                        \
  {                                                                         \
    _Pragma("unroll")                                                       \
    for (int h = 0; h < 2; ++h) {                                           \
      const int row = h * 64 + srow;                                        \
      uint4 ua;                                                             \
      ua.x = pack2(a_pre[h*8+0], a_pre[h*8+1]);                             \
      ua.y = pack2(a_pre[h*8+2], a_pre[h*8+3]);                             \
      ua.z = pack2(a_pre[h*8+4], a_pre[h*8+5]);                             \
      ua.w = pack2(a_pre[h*8+6], a_pre[h*8+7]);                             \
      *(uint4*)&As[p_][row * 32 + sc8] = ua;                                \
    }                                                                       \
  }

  SP_LOAD(0); SP_WRITE(0); __syncthreads();
  int p = 0;
  for (int s = 0; s < 16; ++s) {
    if (s + 1 < 16) SP_LOAD(s + 1);
    const int k0 = s * 32;
    bf16x8 af[4], bq[4];
#pragma unroll
    for (int i = 0; i < 4; ++i) {
      af[i] = *(const bf16x8*)&As[p][(cw + i * 16 + r16) * 32 + quad * 8];
      if (i < 3 || doj3)
        bq[i] = *(const bf16x8*)(wjb[i] + k0);
    }
#pragma unroll
    for (int i = 0; i < 4; ++i)
#pragma unroll
      for (int j = 0; j < 4; ++j)
        if (j < 3 || doj3)
          acc[i][j] = __builtin_amdgcn_mfma_f32_16x16x32_bf16(af[i], bq[j], acc[i][j], 0, 0, 0);
    if (s + 1 < 16) SP_WRITE(p ^ 1);
    __syncthreads();
    p ^= 1;
  }
#undef SP_LOAD
#undef SP_WRITE

  // fold: C layout col=lane&15 (j), row=quad*4+r (c)
  float p00 = 0.f, p01 = 0.f, p10 = 0.f, p11 = 0.f;
#pragma unroll
  for (int j = 0; j < 4; ++j) {
    const int jj = jw + j * 16 + r16;
    if (jj < 98) {
      const int kk = (jj >= 49);
      const int hw = jj - 49 * kk;
      const unsigned short* wa = Wpn + (size_t)hw * 512;         // W[ia][c,hw]
      const unsigned short* wb = Wpn + (size_t)(49 + hw) * 512;  // W[ib][c,hw]
#pragma unroll
      for (int i = 0; i < 4; ++i) {
#pragma unroll
        for (int r = 0; r < 4; ++r) {
          const int c = c0 + cw + i * 16 + quad * 4 + r;
          const float u   = acc[i][j][r];
          const float wav = bf2f(wa[c]);
          const float wbv = bf2f(wb[c]);
          if (kk == 0) { p00 = fmaf(u, wav, p00); p01 = fmaf(u, wbv, p01); }
          else         { p10 = fmaf(u, wav, p10); p11 = fmaf(u, wbv, p11); }
        }
      }
    }
  }

  atomicAdd(&red[0], p00);
  atomicAdd(&red[1], p01);
  atomicAdd(&red[2], p10);
  atomicAdd(&red[3], p11);
  __syncthreads();
  if (t < 4) atomicAdd(&outSPD[n * 4 + t], red[t]);
}

// ---------------------------------------------------------------------------
// SPD fallback (no workspace needed beyond the small scratch)
// ---------------------------------------------------------------------------
__global__ __launch_bounds__(256) void spd_fb_k(
    const float* __restrict__ S, const float* __restrict__ W,
    const int* __restrict__ top2, float* __restrict__ outSPD) {
  __shared__ unsigned short As[128 * 40];
  __shared__ unsigned short Bs[128 * 40];
  __shared__ float red[4];
  const int t = threadIdx.x;
  const int n  = blockIdx.x >> 2;
  const int c0 = (blockIdx.x & 3) * 128;
  const int ia = top2[2 * n];
  const int ib = top2[2 * n + 1];
  const float* Sn = S + (size_t)n * 512 * 512;
  const int lane = t & 63, w = t >> 6;
  const int cw = (w >> 1) * 64, jw = (w & 1) * 64;
  const int r16 = lane & 15, quad = lane >> 4;
  if (t < 4) red[t] = 0.f;
  f32x4 acc[4][4];
#pragma unroll
  for (int i = 0; i < 4; ++i)
#pragma unroll
    for (int j = 0; j < 4; ++j) {
      acc[i][j][0] = 0.f; acc[i][j][1] = 0.f;
      acc[i][j][2] = 0.f; acc[i][j][3] = 0.f;
    }
  const int bj  = t & 127;
  const int bh  = t >> 7;
  const int bkk = (bj >= 49);
  const int bhw = bj - 49 * bkk;
  const bool bvalid = (bj < 98);
  const float* brow = W + (size_t)(bkk ? ib : ia) * KD + bhw;
  for (int d0 = 0; d0 < 512; d0 += 32) {
#pragma unroll
    for (int h = 0; h < 4; ++h) {
      const int idx = h * 256 + t;
      const int row = idx >> 3;
      const int c4  = (idx & 7) << 2;
      float4 av = *(const float4*)(Sn + (size_t)(c0 + row) * 512 + d0 + c4);
      uint2 pa;
      pa.x = pack2(av.x, av.y);
      pa.y = pack2(av.z, av.w);
      *(uint2*)&As[row * 40 + c4] = pa;
    }
#pragma unroll
    for (int dd2 = 0; dd2 < 16; dd2 += 2) {
      const int dd = bh * 16 + dd2;
      const float x0 = bvalid ? brow[(size_t)(d0 + dd) * 49] : 0.f;
      const float x1 = bvalid ? brow[(size_t)(d0 + dd + 1) * 49] : 0.f;
      *(unsigned*)&Bs[bj * 40 + dd] = pack2(x0, x1);
    }
    __syncthreads();
    bf16x8 af[4], bq[4];
#pragma unroll
    for (int i = 0; i < 4; ++i) {
      af[i] = *(const bf16x8*)&As[(cw + i * 16 + r16) * 40 + quad * 8];
      bq[i] = *(const bf16x8*)&Bs[(jw + i * 16 + r16) * 40 + quad * 8];
    }
#pragma unroll
    for (int i = 0; i < 4; ++i)
#pragma unroll
      for (int j = 0; j < 4; ++j)
        acc[i][j] = __builtin_amdgcn_mfma_f32_16x16x32_bf16(af[i], bq[j], acc[i][j], 0, 0, 0);
    __syncthreads();
  }
  float p00 = 0.f, p01 = 0.f, p10 = 0.f, p11 = 0.f;
  const float* Wa = W + (size_t)ia * KD;
  const float* Wb = W + (size_t)ib * KD;
#pragma unroll
  for (int j = 0; j < 4; ++j) {
    const int jj = jw + j * 16 + r16;
    if (jj < 98) {
      const int kk = (jj >= 49);
      const int hw = jj - 49 * kk;
#pragma unroll
      for (int i = 0; i < 4; ++i)
#pragma unroll
        for (int r = 0; r < 4; ++r) {
          const int c = c0 + cw + i * 16 + quad * 4 + r;
          const float u  = acc[i][j][r];
          const float wa = Wa[(size_t)c * 49 + hw];
          const float wb = Wb[(size_t)c * 49 + hw];
          if (kk == 0) { p00 = fmaf(u, wa, p00); p01 = fmaf(u, wb, p01); }
          else         { p10 = fmaf(u, wa, p10); p11 = fmaf(u, wb, p11); }
        }
    }
  }
  atomicAdd(&red[0], p00);
  atomicAdd(&red[1], p01);
  atomicAdd(&red[2], p10);
  atomicAdd(&red[3], p11);
  __syncthreads();
  if (t < 4) atomicAdd(&outSPD[n * 4 + t], red[t]);
}

// ---------------------------------------------------------------------------
extern "C" void kernel_launch(void* const* d_in, const int* in_sizes, int n_in,
                              void* d_out, int out_size, void* d_ws, size_t ws_size,
                              hipStream_t stream) {
  const float* inputR   = (const float*)d_in[0];
  const float* inputSPD = (const float*)d_in[1];
  const float* weight   = (const float*)d_in[2];
  const float* bias     = (const float*)d_in[3];
  float* out = (float*)d_out;

  // ws: [top2 2K][cand 8K][flags 1K][vals 8K] .. 64K ..
  //     [part 28*256*1000*4 = 28.672 MB][Wp 33.55 MB]
  int*   top2    = (int*)d_ws;
  int*   candIdx = (int*)((char*)d_ws + 2048);
  int*   flags   = (int*)((char*)d_ws + 2048 + 8192);
  float* vals    = (float*)((char*)d_ws + 2048 + 8192 + 1024);
  float* part    = (float*)((char*)d_ws + 65536);
  const size_t PART_BYTES = (size_t)ZS * 256 * N_DIM * 4;          // 28,672,000
  unsigned short* Wp = (unsigned short*)((char*)d_ws + 65536 + PART_BYTES);
  const bool bigws = ws_size >= 65536ull + PART_BYTES + 256ull * 65536ull * 2ull;

  if (bigws) {
    rgemm_k<0><<<dim3(448), 256, 0, stream>>>(inputR, weight, part);
    reduce_k<<<dim3(250), 256, 0, stream>>>(part, bias, out);
    top8_k<<<dim3(256), 64, 0, stream>>>(out, top2, candIdx, flags, out + 256000);
    rdot_k<<<dim3(256, 8), 256, 0, stream>>>(inputR, weight, bias, candIdx, flags, vals);
    packsel_k<<<dim3(256, 2), 256, 0, stream>>>(weight, candIdx, flags, vals, Wp);
    spd_k<<<dim3(1024), 256, 0, stream>>>(inputSPD, Wp, out + 256000);
  } else {
    init_bias_k<<<dim3(1000), 256, 0, stream>>>(bias, out);
    rgemm_k<1><<<dim3(448), 256, 0, stream>>>(inputR, weight, out);
    top8_k<<<dim3(256), 64, 0, stream>>>(out, top2, candIdx, flags, out + 256000);
    rdot_k<<<dim3(256, 8), 256, 0, stream>>>(inputR, weight, bias, candIdx, flags, vals);
    select_k<<<dim3(256), 64, 0, stream>>>(vals, candIdx, flags, top2);
    spd_fb_k<<<dim3(1024), 256, 0, stream>>>(inputSPD, weight, top2, out + 256000);
  }
}